// Round 5
// baseline (162.831 us; speedup 1.0000x reference)
//
#include <hip/hip_runtime.h>
#include <hip/hip_bf16.h>

typedef __bf16 bf16;
typedef __bf16 bf16x4 __attribute__((ext_vector_type(4)));
typedef __bf16 bf16x8 __attribute__((ext_vector_type(8)));
typedef float f32x4 __attribute__((ext_vector_type(4)));

#define D 256          // embed dim
#define NHEAD 8
#define HD 32          // head dim
#define NB_ 8
#define LQ_ 256
#define LS_ 4096
#define MQ (NB_ * LQ_)   // 2048
#define MS (NB_ * LS_)   // 32768

// softmax scale folded into Q projection: hd^-0.5 * log2(e)
#define QSCALE 0.25500527f

// ---------------------------------------------------------------------------
// prep: SPb = bf16(source+pe); [Sb = bf16(source)]; QPb = bf16(query+qpe);
//       Wb = bf16(in_proj_w ++ out_w)
// ---------------------------------------------------------------------------
__global__ __launch_bounds__(256) void prep(
    const float* __restrict__ source, const float* __restrict__ source_pe,
    const float* __restrict__ query, const float* __restrict__ query_pe,
    const float* __restrict__ w_in, const float* __restrict__ w_out,
    bf16* __restrict__ SPb, bf16* __restrict__ Sb, bf16* __restrict__ QPb,
    bf16* __restrict__ Wb, int write_sb)
{
    const int NS4 = MS * D / 4;                  // 2097152
    const int NQ4 = MQ * D / 4;                  // 131072
    const int NW4 = (768 * 256 + 256 * 256) / 4; // 65536
    const int total = NS4 + NQ4 + NW4;
    for (int i = blockIdx.x * 256 + threadIdx.x; i < total; i += gridDim.x * 256) {
        if (i < NS4) {
            const float4 s = ((const float4*)source)[i];
            const float4 p = ((const float4*)source_pe)[i];
            bf16x4 osp;
            osp[0] = (bf16)(s.x + p.x); osp[1] = (bf16)(s.y + p.y);
            osp[2] = (bf16)(s.z + p.z); osp[3] = (bf16)(s.w + p.w);
            ((bf16x4*)SPb)[i] = osp;
            if (write_sb) {
                bf16x4 os;
                os[0] = (bf16)s.x; os[1] = (bf16)s.y;
                os[2] = (bf16)s.z; os[3] = (bf16)s.w;
                ((bf16x4*)Sb)[i] = os;
            }
        } else if (i < NS4 + NQ4) {
            const int j = i - NS4;
            const float4 s = ((const float4*)query)[j];
            const float4 p = ((const float4*)query_pe)[j];
            bf16x4 o;
            o[0] = (bf16)(s.x + p.x); o[1] = (bf16)(s.y + p.y);
            o[2] = (bf16)(s.z + p.z); o[3] = (bf16)(s.w + p.w);
            ((bf16x4*)QPb)[j] = o;
        } else {
            const int j = i - NS4 - NQ4;
            const float4 v = (j < 49152) ? ((const float4*)w_in)[j]
                                         : ((const float4*)w_out)[j - 49152];
            bf16x4 o;
            o[0] = (bf16)v.x; o[1] = (bf16)v.y; o[2] = (bf16)v.z; o[3] = (bf16)v.w;
            ((bf16x4*)Wb)[j] = o;
        }
    }
}

// prep2 (fallback only): Sb = bf16(source)
__global__ __launch_bounds__(256) void prep2(
    const float* __restrict__ source, bf16* __restrict__ Sb)
{
    const int NS4 = MS * D / 4;
    for (int i = blockIdx.x * 256 + threadIdx.x; i < NS4; i += gridDim.x * 256) {
        const float4 s = ((const float4*)source)[i];
        bf16x4 o;
        o[0] = (bf16)s.x; o[1] = (bf16)s.y; o[2] = (bf16)s.z; o[3] = (bf16)s.w;
        ((bf16x4*)Sb)[i] = o;
    }
}

// ---------------------------------------------------------------------------
// unified projection GEMM, full-N tiles (128m x 256n), A read ONCE.
// mode 0: id<256 K, id<512 V, id<528 Q.  mode 1: K + Q.  mode 2: V only.
// ---------------------------------------------------------------------------
__global__ __launch_bounds__(256, 2) void gemm_proj_all(
    const bf16* __restrict__ SPb, const bf16* __restrict__ Sb,
    const bf16* __restrict__ QPb, const bf16* __restrict__ Wb,
    const float* __restrict__ in_proj_b,
    bf16* __restrict__ Kb, bf16* __restrict__ Vb, bf16* __restrict__ Qb,
    int mode)
{
    __shared__ bf16 As[128][72];
    __shared__ bf16 Bs[256][72];
    const int tid = threadIdx.x, lane = tid & 63, wid = tid >> 6;
    const int wm = wid >> 1, wn = wid & 1;
    const int g = lane >> 4, q15 = lane & 15;
    const int id = blockIdx.x;

    const bf16* A; const bf16* W; const float* bias; bf16* out;
    float scale = 1.0f; int mblk;
    if (mode == 0) {
        if (id < 256)      { A = SPb; W = Wb + 256 * D; bias = in_proj_b + 256; out = Kb; mblk = id; }
        else if (id < 512) { A = Sb;  W = Wb + 512 * D; bias = in_proj_b + 512; out = Vb; mblk = id - 256; }
        else               { A = QPb; W = Wb;           bias = in_proj_b;       out = Qb; mblk = id - 512; scale = QSCALE; }
    } else if (mode == 1) {
        if (id < 256)      { A = SPb; W = Wb + 256 * D; bias = in_proj_b + 256; out = Kb; mblk = id; }
        else               { A = QPb; W = Wb;           bias = in_proj_b;       out = Qb; mblk = id - 256; scale = QSCALE; }
    } else {
        A = Sb; W = Wb + 512 * D; bias = in_proj_b + 512; out = Vb; mblk = id;
    }

    f32x4 acc[4][8];
    #pragma unroll
    for (int i = 0; i < 4; ++i)
        #pragma unroll
        for (int j = 0; j < 8; ++j) acc[i][j] = (f32x4){0.f, 0.f, 0.f, 0.f};

    const size_t arow0 = (size_t)mblk * 128;

    for (int kk = 0; kk < 4; ++kk) {
        const int d0 = kk * 64;
        #pragma unroll
        for (int i = 0; i < 4; ++i) {
            const int idx = i * 256 + tid;
            const int r = idx >> 3, c = (idx & 7) * 8;
            *(bf16x8*)&As[r][c] = *(const bf16x8*)&A[(arow0 + r) * D + d0 + c];
        }
        #pragma unroll
        for (int i = 0; i < 8; ++i) {
            const int idx = i * 256 + tid;
            const int r = idx >> 3, c = (idx & 7) * 8;
            *(bf16x8*)&Bs[r][c] = *(const bf16x8*)&W[(size_t)r * D + d0 + c];
        }
        __syncthreads();
        #pragma unroll
        for (int h2 = 0; h2 < 2; ++h2) {
            const int ko = h2 * 32 + g * 8;
            bf16x8 af[4], bfr[8];
            #pragma unroll
            for (int i = 0; i < 4; ++i)
                af[i] = *(const bf16x8*)&As[wm * 64 + i * 16 + q15][ko];
            #pragma unroll
            for (int j = 0; j < 8; ++j)
                bfr[j] = *(const bf16x8*)&Bs[wn * 128 + j * 16 + q15][ko];
            #pragma unroll
            for (int i = 0; i < 4; ++i)
                #pragma unroll
                for (int j = 0; j < 8; ++j)
                    acc[i][j] = __builtin_amdgcn_mfma_f32_16x16x32_bf16(
                        af[i], bfr[j], acc[i][j], 0, 0, 0);
        }
        __syncthreads();
    }

    #pragma unroll
    for (int i = 0; i < 4; ++i)
        #pragma unroll
        for (int j = 0; j < 8; ++j) {
            const int n_g = wn * 128 + j * 16 + q15;
            const float b = bias[n_g];
            #pragma unroll
            for (int r = 0; r < 4; ++r) {
                const size_t m_g = arow0 + wm * 64 + i * 16 + g * 4 + r;
                out[m_g * D + n_g] = (bf16)((acc[i][j][r] + b) * scale);
            }
        }
}

// ---------------------------------------------------------------------------
// vt_kernel: V (MS x 256) -> Vt[b*8+h][32 d][4096 kv]  (global transpose)
// grid 2048 = (bh 64) x (kv-tiles 32 of 128).  LDS tile with XOR swizzle.
// ---------------------------------------------------------------------------
__global__ __launch_bounds__(256) void vt_kernel(
    const bf16* __restrict__ V, bf16* __restrict__ Vt)
{
    __shared__ bf16 T[128][40];
    const int tid = threadIdx.x;
    const int id = blockIdx.x;
    const int bh = id >> 5, kt = id & 31;
    const int b = bh >> 3, h = bh & 7;

    const int r0 = tid >> 2, c0 = (tid & 3) * 8;
    #pragma unroll
    for (int p = 0; p < 2; ++p) {
        const int r = p * 64 + r0;
        const bf16x8 v = *(const bf16x8*)
            &V[((size_t)b * LS_ + kt * 128 + r) * D + h * 32 + c0];
        *(bf16x8*)&T[r][c0 ^ (((r >> 3) & 3) << 3)] = v;
    }
    __syncthreads();
    const int dh = tid >> 4, kc = (tid & 15) * 8;
    #pragma unroll
    for (int p = 0; p < 2; ++p) {
        const int dd = p * 16 + dh;
        bf16x8 o;
        #pragma unroll
        for (int e = 0; e < 8; ++e) {
            const int row = kc + e;
            o[e] = T[row][dd ^ (((row >> 3) & 3) << 3)];
        }
        *(bf16x8*)&Vt[((size_t)bh * 32 + dd) * LS_ + kt * 128 + kc] = o;
    }
}

// ---------------------------------------------------------------------------
// split-KV flash attention, LDS-free / barrier-free.
// s = K.Q - 8 (C-init), p = exp2(s); V^T fragments read straight from Vt.
// accp layout: [task][split][lane][8] -> wave writes contiguous 2KB.
// ---------------------------------------------------------------------------
template<int S>
__global__ __launch_bounds__(256, 8) void attn_kernel(
    const bf16* __restrict__ Qb, const bf16* __restrict__ Kb,
    const bf16* __restrict__ Vt,
    float* __restrict__ accp, float* __restrict__ lp)
{
    const int tid = threadIdx.x, lane = tid & 63, wid = tid >> 6;
    const int q15 = lane & 15, g = lane >> 4;
    const int bid = blockIdx.x;
    const int h = bid & 7;
    const int inner = bid >> 3;
    const int b = inner / (S * 4);
    const int rem = inner % (S * 4);
    const int split = rem >> 2, qt = rem & 3;

    const int q0 = b * LQ_ + qt * 64 + wid * 16;
    const bf16x8 qf = *(const bf16x8*)&Qb[(size_t)(q0 + q15) * D + h * HD + g * 8];

    const size_t kvbase = (size_t)b * LS_;
    const int kv0 = split * (LS_ / S);
    const f32x4 minit = (f32x4){-8.f, -8.f, -8.f, -8.f};
    const int rbase = 8 * (q15 >> 2) + (q15 & 3);   // kf row permutation base

    // V^T rows this lane consumes: d = dt*16 + q15
    const bf16* vt0 = Vt + ((size_t)(b * 8 + h) * 32 + q15) * LS_;
    const bf16* vt1 = vt0 + (size_t)16 * LS_;

    float l_run = 0.f;
    f32x4 acc0 = (f32x4){0.f, 0.f, 0.f, 0.f};
    f32x4 acc1 = (f32x4){0.f, 0.f, 0.f, 0.f};

    for (int kc = 0; kc < LS_ / S / 64; ++kc) {
        const int k0 = kv0 + kc * 64;

        // ---- S^T = K Q^T - 8: lane holds 16 kv scores for q = q0 + q15
        f32x4 s[4];
        #pragma unroll
        for (int t = 0; t < 4; ++t) {
            const int row = 32 * (t >> 1) + 4 * (t & 1) + rbase;
            const bf16x8 kf = *(const bf16x8*)
                &Kb[(kvbase + k0 + row) * D + h * HD + g * 8];
            s[t] = __builtin_amdgcn_mfma_f32_16x16x32_bf16(kf, qf, minit, 0, 0, 0);
        }

        // ---- V^T fragments straight from global (L1/L2 served)
        const bf16x8 v00 = *(const bf16x8*)&vt0[k0 + g * 8];
        const bf16x8 v01 = *(const bf16x8*)&vt0[k0 + 32 + g * 8];
        const bf16x8 v10 = *(const bf16x8*)&vt1[k0 + g * 8];
        const bf16x8 v11 = *(const bf16x8*)&vt1[k0 + 32 + g * 8];

        // ---- p = exp2(s); accumulate l; pack P fragments (lane-local)
        bf16x8 pa0, pa1;
        #pragma unroll
        for (int r = 0; r < 4; ++r) {
            const float p0 = exp2f(s[0][r]);
            const float p1 = exp2f(s[1][r]);
            const float p2 = exp2f(s[2][r]);
            const float p3 = exp2f(s[3][r]);
            l_run += (p0 + p1) + (p2 + p3);
            pa0[r]     = (bf16)p0;
            pa0[4 + r] = (bf16)p1;
            pa1[r]     = (bf16)p2;
            pa1[4 + r] = (bf16)p3;
        }

        // ---- O += P V
        acc0 = __builtin_amdgcn_mfma_f32_16x16x32_bf16(pa0, v00, acc0, 0, 0, 0);
        acc0 = __builtin_amdgcn_mfma_f32_16x16x32_bf16(pa1, v01, acc0, 0, 0, 0);
        acc1 = __builtin_amdgcn_mfma_f32_16x16x32_bf16(pa0, v10, acc1, 0, 0, 0);
        acc1 = __builtin_amdgcn_mfma_f32_16x16x32_bf16(pa1, v11, acc1, 0, 0, 0);
    }

    // ---- one final l reduce across the 4 lane-groups (same q15)
    l_run += __shfl_xor(l_run, 16);
    l_run += __shfl_xor(l_run, 32);

    // ---- store partials: wave-contiguous 2KB block
    const int task = (b * 8 + h) * 16 + qt * 4 + wid;
    const size_t base = ((size_t)(task * S + split) * 64 + lane) * 8;
    *(f32x4*)&accp[base]     = acc0;
    *(f32x4*)&accp[base + 4] = acc1;
    if (lane < 16)
        lp[(task * S + split) * 16 + lane] = l_run;
}

// ---------------------------------------------------------------------------
// combine split partials: plain sums.  1 wave per task.
// ---------------------------------------------------------------------------
template<int S>
__global__ __launch_bounds__(256) void attn_combine(
    const float* __restrict__ accp, const float* __restrict__ lp,
    bf16* __restrict__ Ob)
{
    const int tid = threadIdx.x, lane = tid & 63, wid = tid >> 6;
    const int task = blockIdx.x * 4 + wid;
    const int g = lane >> 4, q15 = lane & 15;

    f32x4 o0 = (f32x4){0.f, 0.f, 0.f, 0.f};
    f32x4 o1 = (f32x4){0.f, 0.f, 0.f, 0.f};
    float ll = 0.f;
    #pragma unroll
    for (int s = 0; s < S; ++s) {
        const size_t base = ((size_t)(task * S + s) * 64 + lane) * 8;
        o0 += *(const f32x4*)&accp[base];
        o1 += *(const f32x4*)&accp[base + 4];
        if (lane < 16) ll += lp[(task * S + s) * 16 + lane];
    }

    const int b = task >> 7, h = (task >> 4) & 7, qg = task & 15;
    #pragma unroll
    for (int r = 0; r < 4; ++r) {
        const float inv = 1.f / __shfl(ll, g * 4 + r);
        const size_t row = (size_t)b * LQ_ + qg * 16 + g * 4 + r;
        Ob[row * D + h * HD + q15]      = (bf16)(o0[r] * inv);
        Ob[row * D + h * HD + 16 + q15] = (bf16)(o1[r] * inv);
    }
}

// ---------------------------------------------------------------------------
// fused output projection + bias + residual + LayerNorm.
// ---------------------------------------------------------------------------
__global__ __launch_bounds__(256) void out_ln_kernel(
    const bf16* __restrict__ Ob, const bf16* __restrict__ Wout,
    const float* __restrict__ out_b, const float* __restrict__ query,
    const float* __restrict__ lnw, const float* __restrict__ lnb,
    float* __restrict__ out)
{
    __shared__ bf16 As[128][72];
    __shared__ bf16 Bs[256][72];
    __shared__ float red[2][128][2];
    const int tid = threadIdx.x, lane = tid & 63, wid = tid >> 6;
    const int wm = wid >> 1, wn = wid & 1;
    const int g = lane >> 4, q15 = lane & 15;
    const int mblk = blockIdx.x;

    f32x4 acc[4][8];
    #pragma unroll
    for (int i = 0; i < 4; ++i)
        #pragma unroll
        for (int j = 0; j < 8; ++j) acc[i][j] = (f32x4){0.f, 0.f, 0.f, 0.f};

    for (int kk = 0; kk < 4; ++kk) {
        const int d0 = kk * 64;
        #pragma unroll
        for (int i = 0; i < 4; ++i) {
            const int idx = i * 256 + tid;
            const int r = idx >> 3, c = (idx & 7) * 8;
            *(bf16x8*)&As[r][c] =
                *(const bf16x8*)&Ob[(size_t)(mblk * 128 + r) * D + d0 + c];
        }
        #pragma unroll
        for (int i = 0; i < 8; ++i) {
            const int idx = i * 256 + tid;
            const int r = idx >> 3, c = (idx & 7) * 8;
            *(bf16x8*)&Bs[r][c] = *(const bf16x8*)&Wout[(size_t)r * D + d0 + c];
        }
        __syncthreads();
        #pragma unroll
        for (int h2 = 0; h2 < 2; ++h2) {
            const int ko = h2 * 32 + g * 8;
            bf16x8 af[4], bfr[8];
            #pragma unroll
            for (int i = 0; i < 4; ++i)
                af[i] = *(const bf16x8*)&As[wm * 64 + i * 16 + q15][ko];
            #pragma unroll
            for (int j = 0; j < 8; ++j)
                bfr[j] = *(const bf16x8*)&Bs[wn * 128 + j * 16 + q15][ko];
            #pragma unroll
            for (int i = 0; i < 4; ++i)
                #pragma unroll
                for (int j = 0; j < 8; ++j)
                    acc[i][j] = __builtin_amdgcn_mfma_f32_16x16x32_bf16(
                        af[i], bfr[j], acc[i][j], 0, 0, 0);
        }
        __syncthreads();
    }

    float bl[8], lw[8], lbv[8];
    #pragma unroll
    for (int j = 0; j < 8; ++j) {
        const int n = wn * 128 + j * 16 + q15;
        bl[j] = out_b[n]; lw[j] = lnw[n]; lbv[j] = lnb[n];
    }

    #pragma unroll
    for (int i = 0; i < 4; ++i) {
        #pragma unroll
        for (int r = 0; r < 4; ++r) {
            const size_t m = (size_t)mblk * 128 + wm * 64 + i * 16 + g * 4 + r;
            float s = 0.f, sq = 0.f;
            #pragma unroll
            for (int j = 0; j < 8; ++j) {
                const float v = acc[i][j][r] + bl[j] + query[m * D + wn * 128 + j * 16 + q15];
                acc[i][j][r] = v;
                s += v; sq += v * v;
            }
            s += __shfl_xor(s, 1);  sq += __shfl_xor(sq, 1);
            s += __shfl_xor(s, 2);  sq += __shfl_xor(sq, 2);
            s += __shfl_xor(s, 4);  sq += __shfl_xor(sq, 4);
            s += __shfl_xor(s, 8);  sq += __shfl_xor(sq, 8);
            if (q15 == i * 4 + r) {
                red[wn][wm * 64 + i * 16 + g * 4 + r][0] = s;
                red[wn][wm * 64 + i * 16 + g * 4 + r][1] = sq;
            }
        }
    }
    __syncthreads();

    #pragma unroll
    for (int i = 0; i < 4; ++i)
        #pragma unroll
        for (int r = 0; r < 4; ++r) {
            const int row = wm * 64 + i * 16 + g * 4 + r;
            const float s  = red[0][row][0] + red[1][row][0];
            const float sq = red[0][row][1] + red[1][row][1];
            const float mean = s * (1.f / 256.f);
            const float var  = sq * (1.f / 256.f) - mean * mean;
            const float inv  = rsqrtf(var + 1e-5f);
            const size_t m = (size_t)mblk * 128 + row;
            #pragma unroll
            for (int j = 0; j < 8; ++j)
                out[m * D + wn * 128 + j * 16 + q15] =
                    (acc[i][j][r] - mean) * inv * lw[j] + lbv[j];
        }
}

// ---------------------------------------------------------------------------
extern "C" void kernel_launch(void* const* d_in, const int* in_sizes, int n_in,
                              void* d_out, int out_size, void* d_ws, size_t ws_size,
                              hipStream_t stream) {
    (void)in_sizes; (void)n_in; (void)out_size;
    const float* source    = (const float*)d_in[0];
    const float* query     = (const float*)d_in[1];
    const float* source_pe = (const float*)d_in[2];
    const float* query_pe  = (const float*)d_in[3];
    const float* in_proj_w = (const float*)d_in[4];
    const float* in_proj_b = (const float*)d_in[5];
    const float* out_w     = (const float*)d_in[6];
    const float* out_b     = (const float*)d_in[7];
    const float* ln_w      = (const float*)d_in[8];
    const float* ln_b      = (const float*)d_in[9];

    constexpr int S = 8;
    // workspace layout
    bf16* Wb  = (bf16*)d_ws;                   //  0.5 MB (in_proj ++ out_w)
    bf16* Qb  = Wb + 1024 * 256;               //  1 MB
    bf16* Kb  = Qb + (size_t)MQ * D;           // 16.78 MB
    bf16* Vb  = Kb + (size_t)MS * D;           // 16.78 MB (raw V; dead after vt)
    bf16* Ob  = Vb + (size_t)MS * D;           //  1 MB
    bf16* QPb = Ob + (size_t)MQ * D;           //  1 MB   (later: lp)
    bf16* SPb = QPb + (size_t)MQ * D;          // 16.78 MB (later: Vt)
    bf16* Sb  = SPb + (size_t)MS * D;          // 16.78 MB (fast only; later accp)
    bf16* Vt  = SPb;
    float* lp   = (float*)QPb;
    float* outp = (float*)d_out;

    const size_t need_fast = (size_t)((char*)(Sb + (size_t)MS * D) - (char*)d_ws);
    const bool fast = (ws_size >= need_fast);

    if (fast) {
        prep<<<dim3(2048), dim3(256), 0, stream>>>(
            source, source_pe, query, query_pe, in_proj_w, out_w,
            SPb, Sb, QPb, Wb, 1);
        gemm_proj_all<<<dim3(528), dim3(256), 0, stream>>>(
            SPb, Sb, QPb, Wb, in_proj_b, Kb, Vb, Qb, 0);
        vt_kernel<<<dim3(2048), dim3(256), 0, stream>>>(Vb, Vt);
        float* accp = (float*)Sb;
        attn_kernel<S><<<dim3(256 * S), dim3(256), 0, stream>>>(Qb, Kb, Vt, accp, lp);
        attn_combine<S><<<dim3(256), dim3(256), 0, stream>>>(accp, lp, Ob);
    } else {
        prep<<<dim3(2048), dim3(256), 0, stream>>>(
            source, source_pe, query, query_pe, in_proj_w, out_w,
            SPb, SPb, QPb, Wb, 0);
        gemm_proj_all<<<dim3(272), dim3(256), 0, stream>>>(
            SPb, SPb, QPb, Wb, in_proj_b, Kb, Vb, Qb, 1);      // K + Q
        prep2<<<dim3(2048), dim3(256), 0, stream>>>(source, SPb);
        gemm_proj_all<<<dim3(256), dim3(256), 0, stream>>>(
            SPb, SPb, QPb, Wb, in_proj_b, Kb, Vb, Qb, 2);      // V
        vt_kernel<<<dim3(2048), dim3(256), 0, stream>>>(Vb, Vt); // Vt overlays SPb
        float* accp = (float*)Vb;                                // Vb raw now dead
        attn_kernel<S><<<dim3(256 * S), dim3(256), 0, stream>>>(Qb, Kb, Vt, accp, lp);
        attn_combine<S><<<dim3(256), dim3(256), 0, stream>>>(accp, lp, Ob);
    }

    out_ln_kernel<<<dim3(16), dim3(256), 0, stream>>>(
        Ob, Wb + 768 * 256, out_b, query, ln_w, ln_b, outp);
}

// Round 6
// 94.419 us; speedup vs baseline: 1.7245x; 1.7245x over previous
//
#include <hip/hip_runtime.h>
#include <hip/hip_bf16.h>

typedef __bf16 bf16;
typedef __bf16 bf16x4 __attribute__((ext_vector_type(4)));
typedef __bf16 bf16x8 __attribute__((ext_vector_type(8)));
typedef float f32x4 __attribute__((ext_vector_type(4)));

#define D 256          // embed dim
#define NHEAD 8
#define HD 32          // head dim
#define NB_ 8
#define LQ_ 256
#define LS_ 4096
#define MQ (NB_ * LQ_)   // 2048
#define MS (NB_ * LS_)   // 32768

// softmax scale folded into Q projection: hd^-0.5 * log2(e)
#define QSCALE 0.25500527f

// ---------------------------------------------------------------------------
// prep: SPb = bf16(source+pe); [Sb = bf16(source)]; QPb = bf16(query+qpe);
//       Wb = bf16(in_proj_w ++ out_w)
// ---------------------------------------------------------------------------
__global__ __launch_bounds__(256) void prep(
    const float* __restrict__ source, const float* __restrict__ source_pe,
    const float* __restrict__ query, const float* __restrict__ query_pe,
    const float* __restrict__ w_in, const float* __restrict__ w_out,
    bf16* __restrict__ SPb, bf16* __restrict__ Sb, bf16* __restrict__ QPb,
    bf16* __restrict__ Wb, int write_sb)
{
    const int NS4 = MS * D / 4;                  // 2097152
    const int NQ4 = MQ * D / 4;                  // 131072
    const int NW4 = (768 * 256 + 256 * 256) / 4; // 65536
    const int total = NS4 + NQ4 + NW4;
    for (int i = blockIdx.x * 256 + threadIdx.x; i < total; i += gridDim.x * 256) {
        if (i < NS4) {
            const float4 s = ((const float4*)source)[i];
            const float4 p = ((const float4*)source_pe)[i];
            bf16x4 osp;
            osp[0] = (bf16)(s.x + p.x); osp[1] = (bf16)(s.y + p.y);
            osp[2] = (bf16)(s.z + p.z); osp[3] = (bf16)(s.w + p.w);
            ((bf16x4*)SPb)[i] = osp;
            if (write_sb) {
                bf16x4 os;
                os[0] = (bf16)s.x; os[1] = (bf16)s.y;
                os[2] = (bf16)s.z; os[3] = (bf16)s.w;
                ((bf16x4*)Sb)[i] = os;
            }
        } else if (i < NS4 + NQ4) {
            const int j = i - NS4;
            const float4 s = ((const float4*)query)[j];
            const float4 p = ((const float4*)query_pe)[j];
            bf16x4 o;
            o[0] = (bf16)(s.x + p.x); o[1] = (bf16)(s.y + p.y);
            o[2] = (bf16)(s.z + p.z); o[3] = (bf16)(s.w + p.w);
            ((bf16x4*)QPb)[j] = o;
        } else {
            const int j = i - NS4 - NQ4;
            const float4 v = (j < 49152) ? ((const float4*)w_in)[j]
                                         : ((const float4*)w_out)[j - 49152];
            bf16x4 o;
            o[0] = (bf16)v.x; o[1] = (bf16)v.y; o[2] = (bf16)v.z; o[3] = (bf16)v.w;
            ((bf16x4*)Wb)[j] = o;
        }
    }
}

// prep2 (fallback only): Sb = bf16(source)
__global__ __launch_bounds__(256) void prep2(
    const float* __restrict__ source, bf16* __restrict__ Sb)
{
    const int NS4 = MS * D / 4;
    for (int i = blockIdx.x * 256 + threadIdx.x; i < NS4; i += gridDim.x * 256) {
        const float4 s = ((const float4*)source)[i];
        bf16x4 o;
        o[0] = (bf16)s.x; o[1] = (bf16)s.y; o[2] = (bf16)s.z; o[3] = (bf16)s.w;
        ((bf16x4*)Sb)[i] = o;
    }
}

// ---------------------------------------------------------------------------
// unified projection GEMM, full-N tiles (128m x 256n), A read ONCE.
// mode 0: id<256 K, id<512 V, id<528 Q.  mode 1: K + Q.  mode 2: V only.
// K is stored in Kt fragment layout:  [bh][c64][t:4][lane:64][e:8]
//   kl = 32*(t>>1) + 4*(t&1) + 8*(q15'>>2) + (q15'&3),  d = g'*8 + e,
//   lane' = g'*16 + q15'
// V is stored in Vt2 fragment layout: [bh][c64][f:4][lane:64][e:8]
//   f = (d>>4)*2 + (kl>>5),  kv = (kl>>5)*32 + g'*8 + e,  d = (f>>1)*16 + q15'
// Q stays row-major (scaled).
// ---------------------------------------------------------------------------
__global__ __launch_bounds__(256, 2) void gemm_proj_all(
    const bf16* __restrict__ SPb, const bf16* __restrict__ Sb,
    const bf16* __restrict__ QPb, const bf16* __restrict__ Wb,
    const float* __restrict__ in_proj_b,
    bf16* __restrict__ Kt, bf16* __restrict__ Vt2, bf16* __restrict__ Qb,
    int mode)
{
    __shared__ bf16 As[128][72];
    __shared__ bf16 Bs[256][72];
    const int tid = threadIdx.x, lane = tid & 63, wid = tid >> 6;
    const int wm = wid >> 1, wn = wid & 1;
    const int g = lane >> 4, q15 = lane & 15;
    const int id = blockIdx.x;

    const bf16* A; const bf16* W; const float* bias; bf16* out;
    int omode; int mblk;          // omode: 0=Q row-major, 1=Kt, 2=Vt2
    if (mode == 0) {
        if (id < 256)      { A = SPb; W = Wb + 256 * D; bias = in_proj_b + 256; out = Kt;  mblk = id;       omode = 1; }
        else if (id < 512) { A = Sb;  W = Wb + 512 * D; bias = in_proj_b + 512; out = Vt2; mblk = id - 256; omode = 2; }
        else               { A = QPb; W = Wb;           bias = in_proj_b;       out = Qb;  mblk = id - 512; omode = 0; }
    } else if (mode == 1) {
        if (id < 256)      { A = SPb; W = Wb + 256 * D; bias = in_proj_b + 256; out = Kt;  mblk = id;       omode = 1; }
        else               { A = QPb; W = Wb;           bias = in_proj_b;       out = Qb;  mblk = id - 256; omode = 0; }
    } else {
        A = Sb; W = Wb + 512 * D; bias = in_proj_b + 512; out = Vt2; mblk = id; omode = 2;
    }

    f32x4 acc[4][8];
    #pragma unroll
    for (int i = 0; i < 4; ++i)
        #pragma unroll
        for (int j = 0; j < 8; ++j) acc[i][j] = (f32x4){0.f, 0.f, 0.f, 0.f};

    const size_t arow0 = (size_t)mblk * 128;

    for (int kk = 0; kk < 4; ++kk) {
        const int d0 = kk * 64;
        #pragma unroll
        for (int i = 0; i < 4; ++i) {
            const int idx = i * 256 + tid;
            const int r = idx >> 3, c = (idx & 7) * 8;
            *(bf16x8*)&As[r][c] = *(const bf16x8*)&A[(arow0 + r) * D + d0 + c];
        }
        #pragma unroll
        for (int i = 0; i < 8; ++i) {
            const int idx = i * 256 + tid;
            const int r = idx >> 3, c = (idx & 7) * 8;
            *(bf16x8*)&Bs[r][c] = *(const bf16x8*)&W[(size_t)r * D + d0 + c];
        }
        __syncthreads();
        #pragma unroll
        for (int h2 = 0; h2 < 2; ++h2) {
            const int ko = h2 * 32 + g * 8;
            bf16x8 af[4], bfr[8];
            #pragma unroll
            for (int i = 0; i < 4; ++i)
                af[i] = *(const bf16x8*)&As[wm * 64 + i * 16 + q15][ko];
            #pragma unroll
            for (int j = 0; j < 8; ++j)
                bfr[j] = *(const bf16x8*)&Bs[wn * 128 + j * 16 + q15][ko];
            #pragma unroll
            for (int i = 0; i < 4; ++i)
                #pragma unroll
                for (int j = 0; j < 8; ++j)
                    acc[i][j] = __builtin_amdgcn_mfma_f32_16x16x32_bf16(
                        af[i], bfr[j], acc[i][j], 0, 0, 0);
        }
        __syncthreads();
    }

    if (omode == 0) {
        #pragma unroll
        for (int i = 0; i < 4; ++i)
            #pragma unroll
            for (int j = 0; j < 8; ++j) {
                const int n_g = wn * 128 + j * 16 + q15;
                const float b = bias[n_g];
                #pragma unroll
                for (int r = 0; r < 4; ++r) {
                    const size_t m_g = arow0 + wm * 64 + i * 16 + g * 4 + r;
                    out[m_g * D + n_g] = (bf16)((acc[i][j][r] + b) * QSCALE);
                }
            }
    } else if (omode == 1) {
        // K -> Kt fragment layout
        #pragma unroll
        for (int i = 0; i < 4; ++i)
            #pragma unroll
            for (int j = 0; j < 8; ++j) {
                const int n_g = wn * 128 + j * 16 + q15;
                const int h = n_g >> 5, d = n_g & 31;
                const int gp = d >> 3, e = d & 7;
                const float b = bias[n_g];
                #pragma unroll
                for (int r = 0; r < 4; ++r) {
                    const size_t m_g = arow0 + wm * 64 + i * 16 + g * 4 + r;
                    const int bb = (int)(m_g >> 12);
                    const int c = (int)((m_g & 4095) >> 6);
                    const int kl = (int)(m_g & 63);
                    const int t = ((kl >> 5) << 1) | ((kl >> 2) & 1);
                    const int q15p = ((kl >> 3) & 3) * 4 + (kl & 3);
                    out[((size_t)(bb * 8 + h) * 64 + c) * 2048
                        + t * 512 + (gp * 16 + q15p) * 8 + e] = (bf16)(acc[i][j][r] + b);
                }
            }
    } else {
        // V -> Vt2 fragment layout (r-quad vectorizes: e0 = (g*4)&7 in {0,4})
        #pragma unroll
        for (int i = 0; i < 4; ++i)
            #pragma unroll
            for (int j = 0; j < 8; ++j) {
                const int n_g = wn * 128 + j * 16 + q15;
                const int h = n_g >> 5, d = n_g & 31;
                const int dt = d >> 4, q15p = d & 15;
                const float b = bias[n_g];
                const size_t m_g0 = arow0 + wm * 64 + i * 16 + g * 4;
                const int bb = (int)(m_g0 >> 12);
                const int c = (int)((m_g0 & 4095) >> 6);
                const int kl0 = (int)(m_g0 & 63);
                const int half = kl0 >> 5, gp = (kl0 >> 3) & 3, e0 = kl0 & 7;
                const int f = dt * 2 + half;
                bf16x4 o;
                #pragma unroll
                for (int r = 0; r < 4; ++r) o[r] = (bf16)(acc[i][j][r] + b);
                *(bf16x4*)&out[((size_t)(bb * 8 + h) * 64 + c) * 2048
                               + f * 512 + (gp * 16 + q15p) * 8 + e0] = o;
            }
    }
}

// ---------------------------------------------------------------------------
// split-KV flash attention: LDS-free, barrier-free, fully-coalesced loads.
// Per 64-kv chunk: K = 4 contiguous 1KB wave loads, V = 4 contiguous 1KB.
// s = K.Q - 8 (C-init), p = exp2(s); plain-sum combine.
// ---------------------------------------------------------------------------
template<int S>
__global__ __launch_bounds__(256, 8) void attn_kernel(
    const bf16* __restrict__ Qb, const bf16* __restrict__ Kt,
    const bf16* __restrict__ Vt2,
    float* __restrict__ accp, float* __restrict__ lp)
{
    const int tid = threadIdx.x, lane = tid & 63, wid = tid >> 6;
    const int q15 = lane & 15, g = lane >> 4;
    const int bid = blockIdx.x;
    const int h = bid & 7;
    const int inner = bid >> 3;
    const int b = inner / (S * 4);
    const int rem = inner % (S * 4);
    const int split = rem >> 2, qt = rem & 3;
    constexpr int CHUNKS = LS_ / S / 64;

    const int q0 = b * LQ_ + qt * 64 + wid * 16;
    const bf16x8 qf = *(const bf16x8*)&Qb[(size_t)(q0 + q15) * D + h * HD + g * 8];

    const f32x4 minit = (f32x4){-8.f, -8.f, -8.f, -8.f};
    const size_t cbase = ((size_t)(b * 8 + h) * 64 + split * CHUNKS) * 2048;
    const bf16* kp = Kt + cbase + lane * 8;
    const bf16* vp = Vt2 + cbase + lane * 8;

    float l_run = 0.f;
    f32x4 acc0 = (f32x4){0.f, 0.f, 0.f, 0.f};
    f32x4 acc1 = (f32x4){0.f, 0.f, 0.f, 0.f};

    for (int kc = 0; kc < CHUNKS; ++kc) {
        const size_t co = (size_t)kc * 2048;

        bf16x8 kf[4], vf[4];
        #pragma unroll
        for (int t = 0; t < 4; ++t) kf[t] = *(const bf16x8*)&kp[co + t * 512];
        #pragma unroll
        for (int f = 0; f < 4; ++f) vf[f] = *(const bf16x8*)&vp[co + f * 512];

        // ---- S^T = K Q^T - 8
        f32x4 s[4];
        #pragma unroll
        for (int t = 0; t < 4; ++t)
            s[t] = __builtin_amdgcn_mfma_f32_16x16x32_bf16(kf[t], qf, minit, 0, 0, 0);

        // ---- p = exp2(s); accumulate l; pack P fragments (lane-local)
        bf16x8 pa0, pa1;
        #pragma unroll
        for (int r = 0; r < 4; ++r) {
            const float p0 = exp2f(s[0][r]);
            const float p1 = exp2f(s[1][r]);
            const float p2 = exp2f(s[2][r]);
            const float p3 = exp2f(s[3][r]);
            l_run += (p0 + p1) + (p2 + p3);
            pa0[r]     = (bf16)p0;
            pa0[4 + r] = (bf16)p1;
            pa1[r]     = (bf16)p2;
            pa1[4 + r] = (bf16)p3;
        }

        // ---- O += P V
        acc0 = __builtin_amdgcn_mfma_f32_16x16x32_bf16(pa0, vf[0], acc0, 0, 0, 0);
        acc0 = __builtin_amdgcn_mfma_f32_16x16x32_bf16(pa1, vf[1], acc0, 0, 0, 0);
        acc1 = __builtin_amdgcn_mfma_f32_16x16x32_bf16(pa0, vf[2], acc1, 0, 0, 0);
        acc1 = __builtin_amdgcn_mfma_f32_16x16x32_bf16(pa1, vf[3], acc1, 0, 0, 0);
    }

    // ---- one final l reduce across the 4 lane-groups (same q15)
    l_run += __shfl_xor(l_run, 16);
    l_run += __shfl_xor(l_run, 32);

    // ---- store partials: wave-contiguous 2KB block
    const int task = (b * 8 + h) * 16 + qt * 4 + wid;
    const size_t base = ((size_t)(task * S + split) * 64 + lane) * 8;
    *(f32x4*)&accp[base]     = acc0;
    *(f32x4*)&accp[base + 4] = acc1;
    if (lane < 16)
        lp[(task * S + split) * 16 + lane] = l_run;
}

// ---------------------------------------------------------------------------
// combine split partials: plain sums.  1 wave per task.
// ---------------------------------------------------------------------------
template<int S>
__global__ __launch_bounds__(256) void attn_combine(
    const float* __restrict__ accp, const float* __restrict__ lp,
    bf16* __restrict__ Ob)
{
    const int tid = threadIdx.x, lane = tid & 63, wid = tid >> 6;
    const int task = blockIdx.x * 4 + wid;
    const int g = lane >> 4, q15 = lane & 15;

    f32x4 o0 = (f32x4){0.f, 0.f, 0.f, 0.f};
    f32x4 o1 = (f32x4){0.f, 0.f, 0.f, 0.f};
    float ll = 0.f;
    #pragma unroll
    for (int s = 0; s < S; ++s) {
        const size_t base = ((size_t)(task * S + s) * 64 + lane) * 8;
        o0 += *(const f32x4*)&accp[base];
        o1 += *(const f32x4*)&accp[base + 4];
        if (lane < 16) ll += lp[(task * S + s) * 16 + lane];
    }

    const int b = task >> 7, h = (task >> 4) & 7, qg = task & 15;
    #pragma unroll
    for (int r = 0; r < 4; ++r) {
        const float inv = 1.f / __shfl(ll, g * 4 + r);
        const size_t row = (size_t)b * LQ_ + qg * 16 + g * 4 + r;
        Ob[row * D + h * HD + q15]      = (bf16)(o0[r] * inv);
        Ob[row * D + h * HD + 16 + q15] = (bf16)(o1[r] * inv);
    }
}

// ---------------------------------------------------------------------------
// fused output projection + bias + residual + LayerNorm.
// ---------------------------------------------------------------------------
__global__ __launch_bounds__(256) void out_ln_kernel(
    const bf16* __restrict__ Ob, const bf16* __restrict__ Wout,
    const float* __restrict__ out_b, const float* __restrict__ query,
    const float* __restrict__ lnw, const float* __restrict__ lnb,
    float* __restrict__ out)
{
    __shared__ bf16 As[128][72];
    __shared__ bf16 Bs[256][72];
    __shared__ float red[2][128][2];
    const int tid = threadIdx.x, lane = tid & 63, wid = tid >> 6;
    const int wm = wid >> 1, wn = wid & 1;
    const int g = lane >> 4, q15 = lane & 15;
    const int mblk = blockIdx.x;

    f32x4 acc[4][8];
    #pragma unroll
    for (int i = 0; i < 4; ++i)
        #pragma unroll
        for (int j = 0; j < 8; ++j) acc[i][j] = (f32x4){0.f, 0.f, 0.f, 0.f};

    for (int kk = 0; kk < 4; ++kk) {
        const int d0 = kk * 64;
        #pragma unroll
        for (int i = 0; i < 4; ++i) {
            const int idx = i * 256 + tid;
            const int r = idx >> 3, c = (idx & 7) * 8;
            *(bf16x8*)&As[r][c] =
                *(const bf16x8*)&Ob[(size_t)(mblk * 128 + r) * D + d0 + c];
        }
        #pragma unroll
        for (int i = 0; i < 8; ++i) {
            const int idx = i * 256 + tid;
            const int r = idx >> 3, c = (idx & 7) * 8;
            *(bf16x8*)&Bs[r][c] = *(const bf16x8*)&Wout[(size_t)r * D + d0 + c];
        }
        __syncthreads();
        #pragma unroll
        for (int h2 = 0; h2 < 2; ++h2) {
            const int ko = h2 * 32 + g * 8;
            bf16x8 af[4], bfr[8];
            #pragma unroll
            for (int i = 0; i < 4; ++i)
                af[i] = *(const bf16x8*)&As[wm * 64 + i * 16 + q15][ko];
            #pragma unroll
            for (int j = 0; j < 8; ++j)
                bfr[j] = *(const bf16x8*)&Bs[wn * 128 + j * 16 + q15][ko];
            #pragma unroll
            for (int i = 0; i < 4; ++i)
                #pragma unroll
                for (int j = 0; j < 8; ++j)
                    acc[i][j] = __builtin_amdgcn_mfma_f32_16x16x32_bf16(
                        af[i], bfr[j], acc[i][j], 0, 0, 0);
        }
        __syncthreads();
    }

    float bl[8], lw[8], lbv[8];
    #pragma unroll
    for (int j = 0; j < 8; ++j) {
        const int n = wn * 128 + j * 16 + q15;
        bl[j] = out_b[n]; lw[j] = lnw[n]; lbv[j] = lnb[n];
    }

    #pragma unroll
    for (int i = 0; i < 4; ++i) {
        #pragma unroll
        for (int r = 0; r < 4; ++r) {
            const size_t m = (size_t)mblk * 128 + wm * 64 + i * 16 + g * 4 + r;
            float s = 0.f, sq = 0.f;
            #pragma unroll
            for (int j = 0; j < 8; ++j) {
                const float v = acc[i][j][r] + bl[j] + query[m * D + wn * 128 + j * 16 + q15];
                acc[i][j][r] = v;
                s += v; sq += v * v;
            }
            s += __shfl_xor(s, 1);  sq += __shfl_xor(sq, 1);
            s += __shfl_xor(s, 2);  sq += __shfl_xor(sq, 2);
            s += __shfl_xor(s, 4);  sq += __shfl_xor(sq, 4);
            s += __shfl_xor(s, 8);  sq += __shfl_xor(sq, 8);
            if (q15 == i * 4 + r) {
                red[wn][wm * 64 + i * 16 + g * 4 + r][0] = s;
                red[wn][wm * 64 + i * 16 + g * 4 + r][1] = sq;
            }
        }
    }
    __syncthreads();

    #pragma unroll
    for (int i = 0; i < 4; ++i)
        #pragma unroll
        for (int r = 0; r < 4; ++r) {
            const int row = wm * 64 + i * 16 + g * 4 + r;
            const float s  = red[0][row][0] + red[1][row][0];
            const float sq = red[0][row][1] + red[1][row][1];
            const float mean = s * (1.f / 256.f);
            const float var  = sq * (1.f / 256.f) - mean * mean;
            const float inv  = rsqrtf(var + 1e-5f);
            const size_t m = (size_t)mblk * 128 + row;
            #pragma unroll
            for (int j = 0; j < 8; ++j)
                out[m * D + wn * 128 + j * 16 + q15] =
                    (acc[i][j][r] - mean) * inv * lw[j] + lbv[j];
        }
}

// ---------------------------------------------------------------------------
extern "C" void kernel_launch(void* const* d_in, const int* in_sizes, int n_in,
                              void* d_out, int out_size, void* d_ws, size_t ws_size,
                              hipStream_t stream) {
    (void)in_sizes; (void)n_in; (void)out_size;
    const float* source    = (const float*)d_in[0];
    const float* query     = (const float*)d_in[1];
    const float* source_pe = (const float*)d_in[2];
    const float* query_pe  = (const float*)d_in[3];
    const float* in_proj_w = (const float*)d_in[4];
    const float* in_proj_b = (const float*)d_in[5];
    const float* out_w     = (const float*)d_in[6];
    const float* out_b     = (const float*)d_in[7];
    const float* ln_w      = (const float*)d_in[8];
    const float* ln_b      = (const float*)d_in[9];

    constexpr int S = 8;
    // workspace layout
    bf16* Wb  = (bf16*)d_ws;                   //  0.5 MB (in_proj ++ out_w)
    bf16* Qb  = Wb + 1024 * 256;               //  1 MB
    bf16* Kt  = Qb + (size_t)MQ * D;           // 16.78 MB (fragment layout)
    bf16* Vt2 = Kt + (size_t)MS * D;           // 16.78 MB (fragment layout)
    bf16* Ob  = Vt2 + (size_t)MS * D;          //  1 MB
    bf16* QPb = Ob + (size_t)MQ * D;           //  1 MB   (later: lp)
    bf16* SPb = QPb + (size_t)MQ * D;          // 16.78 MB (later: accp fallback)
    bf16* Sb  = SPb + (size_t)MS * D;          // 16.78 MB (fast only; later accp)
    float* lp   = (float*)QPb;
    float* outp = (float*)d_out;

    const size_t need_fast = (size_t)((char*)(Sb + (size_t)MS * D) - (char*)d_ws);
    const bool fast = (ws_size >= need_fast);

    if (fast) {
        prep<<<dim3(2048), dim3(256), 0, stream>>>(
            source, source_pe, query, query_pe, in_proj_w, out_w,
            SPb, Sb, QPb, Wb, 1);
        gemm_proj_all<<<dim3(528), dim3(256), 0, stream>>>(
            SPb, Sb, QPb, Wb, in_proj_b, Kt, Vt2, Qb, 0);
        float* accp = (float*)Sb;
        attn_kernel<S><<<dim3(256 * S), dim3(256), 0, stream>>>(Qb, Kt, Vt2, accp, lp);
        attn_combine<S><<<dim3(256), dim3(256), 0, stream>>>(accp, lp, Ob);
    } else {
        prep<<<dim3(2048), dim3(256), 0, stream>>>(
            source, source_pe, query, query_pe, in_proj_w, out_w,
            SPb, SPb, QPb, Wb, 0);
        gemm_proj_all<<<dim3(272), dim3(256), 0, stream>>>(
            SPb, SPb, QPb, Wb, in_proj_b, Kt, Vt2, Qb, 1);     // K + Q
        prep2<<<dim3(2048), dim3(256), 0, stream>>>(source, SPb);
        gemm_proj_all<<<dim3(256), dim3(256), 0, stream>>>(
            SPb, SPb, QPb, Wb, in_proj_b, Kt, Vt2, Qb, 2);     // V
        float* accp = (float*)SPb;                             // SPb dead now
        attn_kernel<S><<<dim3(256 * S), dim3(256), 0, stream>>>(Qb, Kt, Vt2, accp, lp);
        attn_combine<S><<<dim3(256), dim3(256), 0, stream>>>(accp, lp, Ob);
    }

    out_ln_kernel<<<dim3(16), dim3(256), 0, stream>>>(
        Ob, Wb + 768 * 256, out_b, query, ln_w, ln_b, outp);
}